// Round 7
// baseline (95.528 us; speedup 1.0000x reference)
//
#include <hip/hip_runtime.h>
#include <stdint.h>

// Grouped linear: y[z] = coeff * x[z] @ W[idx[z]], idx sorted.
// C=8, U=V=512, Z=32768, fp32 in/out, bf16 MFMA compute.
//
// R7: A fragments load DIRECT from x to registers (no A-LDS, no ds_writes,
// no lgkm coupling); fp32->bf16 cvt in regs. B via global_load_lds from
// pre-tiled bf16 ws into 3 rotating LDS buffers (2-iteration flight).
// One raw s_barrier + counted vmcnt(10) per K-step; sched_barrier(0)
// region boundaries keep the vmcnt arithmetic exact (each region = 10 VM ops).

#define Cg 8
#define Ud 512
#define Vd 512
#define Zd 32768

#define BM 128
#define BN 128
#define BK 32
#define KT 16

#define TILE_US 4096             // 128 cols * 32 k bf16 = 8 KiB
#define NBN 4
#define NBM_MAX 263              // sum ceil(cnt_g/128) <= 256+7
#define GRID_GEMM (NBM_MAX * NBN)

#define WSW_US (Cg * NBN * KT * TILE_US)     // 4 MiB of bf16
#define WS_NEEDED ((size_t)WSW_US * 2 + 64)

typedef __attribute__((ext_vector_type(8))) short bf16x8;
typedef __attribute__((ext_vector_type(4))) float f32x4;
typedef __attribute__((ext_vector_type(4))) unsigned short us4;
typedef __attribute__((ext_vector_type(4))) float float4v;
typedef __attribute__((ext_vector_type(4))) unsigned int u32x4;

typedef __attribute__((address_space(3))) unsigned int lds_uint;
typedef const __attribute__((address_space(1))) unsigned int gbl_uint;

__device__ __forceinline__ unsigned short f2bf(float f) {
    unsigned int u = __float_as_uint(f);
    u += 0x7fffu + ((u >> 16) & 1u);   // round-to-nearest-even
    return (unsigned short)(u >> 16);
}
__device__ __forceinline__ unsigned int pk2(float lo, float hi) {
    return (unsigned int)f2bf(lo) | ((unsigned int)f2bf(hi) << 16);
}

// B subtile layout within one [128 c][32 k] tile (ushort offset):
//   (c>>4)*512 + (k>>3)*128 + (c&15)*8 + (k&7)
// Frag read (lane l): byte = ct*1024 + l4*256 + l15*16 -> contiguous 1 KiB
// per frag across the wave: conflict-free ds_read_b128 (R2/R6-verified).

// ---------------- w converter (+ group starts) ----------------

__global__ __launch_bounds__(256)
void convert_w(const float* __restrict__ w, const int* __restrict__ idx,
               unsigned short* __restrict__ wsw, int* __restrict__ starts)
{
    const int t = blockIdx.x * 256 + threadIdx.x;    // 524288 tasks
    const int g   = t >> 16;
    const int rem = t & 65535;
    const int u0  = (rem >> 9) << 2;                 // 4 k-rows
    const int v   = rem & 511;
    const float* src = w + ((size_t)g << 18) + (size_t)u0 * Vd + v;
    us4 p;
    p[0] = f2bf(src[0]);
    p[1] = f2bf(src[Vd]);
    p[2] = f2bf(src[2 * Vd]);
    p[3] = f2bf(src[3 * Vd]);
    const int r = v & 127, k = u0 & 31;
    const int tile = (g * NBN + (v >> 7)) * KT + (u0 >> 5);
    const int off  = tile * TILE_US
                   + ((r >> 4) << 9) + ((k >> 3) << 7) + ((r & 15) << 3) + (k & 7);
    *(us4*)(wsw + off) = p;

    if (blockIdx.x == 0 && threadIdx.x < 9) {
        const int gq = threadIdx.x;
        int lo = 0;
        if (gq >= 8) lo = Zd;
        else {
            int hi = Zd;
            while (lo < hi) { int mid = (lo + hi) >> 1;
                              if (idx[mid] < gq) lo = mid + 1; else hi = mid; }
        }
        starts[gq] = lo;
    }
}

// ---------------- GEMM ----------------

// A-frag direct load: lane l covers row (mi*16 + l15), k = l4*8 .. +7 (32B).
#define LDA(KTV, BI) do {                                                     \
    _Pragma("unroll")                                                         \
    for (int mi_ = 0; mi_ < 4; ++mi_) {                                       \
        const float* p_ = ap[mi_] + (KTV) * BK;                               \
        ab[BI][mi_][0] = *(const float4v*)(p_);                               \
        ab[BI][mi_][1] = *(const float4v*)(p_ + 4);                           \
    } } while (0)

#define GLB(KTV, J) do {                                                      \
    const unsigned short* s_ = wB + (size_t)(KTV) * TILE_US;                  \
    __builtin_amdgcn_global_load_lds((gbl_uint*)(s_ + bo),                    \
                                     (lds_uint*)(&Bs[J][bo]), 16, 0, 0);      \
    __builtin_amdgcn_global_load_lds((gbl_uint*)(s_ + bo + 2048),             \
                                     (lds_uint*)(&Bs[J][bo + 2048]), 16, 0, 0); \
  } while (0)

#define CVT_CMP(BI, J) do {                                                   \
    bf16x8 a_[4], b_[4];                                                      \
    _Pragma("unroll")                                                         \
    for (int mi_ = 0; mi_ < 4; ++mi_) {                                       \
        u32x4 t_;                                                             \
        t_[0] = pk2(ab[BI][mi_][0][0], ab[BI][mi_][0][1]);                    \
        t_[1] = pk2(ab[BI][mi_][0][2], ab[BI][mi_][0][3]);                    \
        t_[2] = pk2(ab[BI][mi_][1][0], ab[BI][mi_][1][1]);                    \
        t_[3] = pk2(ab[BI][mi_][1][2], ab[BI][mi_][1][3]);                    \
        a_[mi_] = __builtin_bit_cast(bf16x8, t_);                             \
    }                                                                         \
    _Pragma("unroll")                                                         \
    for (int ni_ = 0; ni_ < 4; ++ni_)                                         \
        b_[ni_] = *(const bf16x8*)(&Bs[J][((wn4 + ni_) << 9) + fr]);          \
    _Pragma("unroll")                                                         \
    for (int mi_ = 0; mi_ < 4; ++mi_)                                         \
        _Pragma("unroll")                                                     \
        for (int ni_ = 0; ni_ < 4; ++ni_)                                     \
            acc[mi_][ni_] = __builtin_amdgcn_mfma_f32_16x16x32_bf16(          \
                a_[mi_], b_[ni_], acc[mi_][ni_], 0, 0, 0);                    \
  } while (0)

#define WAITV(N) asm volatile("s_waitcnt vmcnt(" #N ")" ::: "memory")

__global__ __launch_bounds__(256, 2)
void sgl_gemm(const float* __restrict__ x,
              const unsigned short* __restrict__ wsw,
              const int* __restrict__ starts,
              const float* __restrict__ coeff,
              float* __restrict__ y)
{
    __shared__ unsigned short Bs[3][TILE_US];    // 24 KiB

    const int tid = threadIdx.x, lane = tid & 63, wave = tid >> 6;
    const int l15 = lane & 15, l4 = lane >> 4;

    // bijective XCD swizzle (m204): nwg=1052, q=131, r=4; consecutive wk
    // share bmp -> the 4 bn-blocks of one x-panel land on one XCD (L2 reuse).
    const int bid = blockIdx.x;
    const int xcd = bid & 7, io = bid >> 3;
    const int wk  = (xcd < 4) ? xcd * 132 + io : 528 + (xcd - 4) * 131 + io;
    const int bmp = wk >> 2, bn = wk & 3;

    // locate group for this padded row-block
    int s[9];
#pragma unroll
    for (int i = 0; i < 9; ++i) s[i] = starts[i];
    int g = -1, lblk = 0, ab_ = 0;
#pragma unroll
    for (int gg = 0; gg < 8; ++gg) {
        const int c  = s[gg + 1] - s[gg];
        const int nb = (c + BM - 1) >> 7;
        if (g < 0 && bmp < ab_ + nb) { g = gg; lblk = bmp - ab_; }
        ab_ += nb;
    }
    if (g < 0) return;                          // uniform per block
    const int start = s[g];
    const int cnt   = s[g + 1] - s[g];
    const int j0    = lblk << 7;

    // A row pointers (4 m-tiles per wave); padded rows clamped (masked at store)
    const int wrow = (wave >> 1) * 64;
    const float* ap[4];
#pragma unroll
    for (int mi = 0; mi < 4; ++mi) {
        int r = j0 + wrow + mi * 16 + l15;
        if (r >= cnt) r = cnt - 1;
        ap[mi] = x + (size_t)(start + r) * Ud + (l4 << 3);
    }

    // B staging geometry
    const unsigned short* wB = wsw + (size_t)((g * NBN + bn) * KT) * TILE_US;
    const int bo  = tid * 8;
    const int wn4 = (wave & 1) << 2;
    const int fr  = (l4 << 7) + (l15 << 3);

    f32x4 acc[4][4];
#pragma unroll
    for (int mi = 0; mi < 4; ++mi)
#pragma unroll
        for (int ni = 0; ni < 4; ++ni)
            acc[mi][ni] = f32x4{0.f, 0.f, 0.f, 0.f};

    float4v ab[2][4][2];    // two A reg-stages (fully unrolled -> static idx)

    // prologue: region P0 = {GLB(0), LDA(0)} [10 VM ops], then boundary,
    // then P1 opens with GLB(1); loop's first LDA(1) completes P1 [10].
    GLB(0, 0);
    LDA(0, 0);
    __builtin_amdgcn_sched_barrier(0);
    GLB(1, 1);

#pragma unroll
    for (int kt = 0; kt < 15; ++kt) {
        LDA(kt + 1, (kt + 1) & 1);              // closes current region [10]
        WAITV(10);                              // drain all older regions:
                                                //   B(kt) in LDS, A(kt) in regs
        __builtin_amdgcn_s_barrier();           // all threads' B(kt) complete
        __builtin_amdgcn_sched_barrier(0);      // region boundary
        if (kt < 14) GLB(kt + 2, (kt + 2) % 3); // overwrite-safe: readers of
                                                // this buf finished pre-barrier
        CVT_CMP(kt & 1, kt % 3);
    }
    // kt = 15: region R(14) had no VM ops; drain the last region fully
    WAITV(0);
    __builtin_amdgcn_s_barrier();
    __builtin_amdgcn_sched_barrier(0);
    CVT_CMP(1, 0);

    // epilogue: C/D col=lane&15, row=(lane>>4)*4+q; mask padded rows
    const float cf = coeff[0];
    const bool full = (j0 + BM) <= cnt;
#pragma unroll
    for (int mi = 0; mi < 4; ++mi) {
        const int rb = wrow + mi * 16 + l4 * 4;
#pragma unroll
        for (int ni = 0; ni < 4; ++ni) {
            const int c = bn * BN + ((wave & 1) << 6) + ni * 16 + l15;
#pragma unroll
            for (int q = 0; q < 4; ++q) {
                if (full || (j0 + rb + q) < cnt)
                    y[(size_t)(start + j0 + rb + q) * Vd + c] = acc[mi][ni][q] * cf;
            }
        }
    }
}

// ---------------- safety-net fallback (ws too small; not expected) --------

__global__ __launch_bounds__(256)
void sgl_naive(const float* __restrict__ w, const float* __restrict__ x,
               const int* __restrict__ idx, const float* __restrict__ coeff,
               float* __restrict__ y)
{
    __shared__ float xs[Ud];
    const int z = blockIdx.x;
    const int g = idx[z];
    for (int u = threadIdx.x; u < Ud; u += 256) xs[u] = x[(size_t)z * Ud + u];
    __syncthreads();
    const float* Wg = w + (size_t)g * (Ud * Vd);
    const float cf = coeff[0];
    for (int v = threadIdx.x; v < Vd; v += 256) {
        float acc = 0.f;
        for (int u = 0; u < Ud; ++u) acc += xs[u] * Wg[(size_t)u * Vd + v];
        y[(size_t)z * Vd + v] = acc * cf;
    }
}

extern "C" void kernel_launch(void* const* d_in, const int* in_sizes, int n_in,
                              void* d_out, int out_size, void* d_ws, size_t ws_size,
                              hipStream_t stream) {
    const float* w     = (const float*)d_in[0];
    const float* x     = (const float*)d_in[1];
    const int*   idx   = (const int*)d_in[2];
    const float* coeff = (const float*)d_in[3];
    float* y = (float*)d_out;

    if (ws_size >= WS_NEEDED) {
        unsigned short* wsw = (unsigned short*)d_ws;
        int* starts = (int*)((char*)d_ws + (size_t)WSW_US * 2);
        hipLaunchKernelGGL(convert_w, dim3(2048), dim3(256), 0, stream,
                           w, idx, wsw, starts);
        hipLaunchKernelGGL(sgl_gemm, dim3(GRID_GEMM), dim3(256), 0, stream,
                           x, wsw, starts, coeff, y);
    } else {
        hipLaunchKernelGGL(sgl_naive, dim3(Zd), dim3(256), 0, stream,
                           w, x, idx, coeff, y);
    }
}

// Round 8
// 62.448 us; speedup vs baseline: 1.5297x; 1.5297x over previous
//
#include <hip/hip_runtime.h>
#include <stdint.h>

// Grouped linear: y[z] = coeff * x[z] @ W[idx[z]], idx sorted.
// C=8, U=V=512, Z=32768, fp32 in/out, bf16 MFMA compute.
//
// R8: R6's counted-vmcnt schedule scaled to BM=256,BN=256 (512 thr, 8 waves)
// to halve W re-reads (nbm 263->135) and halve x re-reads (bn 4->2, paired
// on one XCD so the 2nd read L2-hits). A: coalesced fp32 reg-stage -> cvt ->
// ds_write; B: global_load_lds from pre-tiled bf16 ws; raw s_barrier with
// vmcnt(4) so A(kt+2) reg-prefetch stays in flight across barriers.

#define Cg 8
#define Ud 512
#define Vd 512
#define Zd 32768

#define BM 256
#define BN 256
#define BK 32
#define KT 16

#define TILE_US 8192             // 256 x 32 bf16 = 16 KiB
#define NBN 2
#define NBM_MAX 135              // sum ceil(cnt_g/256) <= 128+7
#define GRID_GEMM (NBM_MAX * NBN)    // 270

#define WSW_US (Cg * NBN * KT * TILE_US)     // 4 MiB of bf16
#define WS_NEEDED ((size_t)WSW_US * 2 + 64)

typedef __attribute__((ext_vector_type(8))) short bf16x8;
typedef __attribute__((ext_vector_type(4))) float f32x4;
typedef __attribute__((ext_vector_type(4))) unsigned short us4;
typedef __attribute__((ext_vector_type(4))) float float4v;
typedef __attribute__((ext_vector_type(4))) unsigned int u32x4;

typedef __attribute__((address_space(3))) unsigned int lds_uint;
typedef const __attribute__((address_space(1))) unsigned int gbl_uint;

__device__ __forceinline__ unsigned short f2bf(float f) {
    unsigned int u = __float_as_uint(f);
    u += 0x7fffu + ((u >> 16) & 1u);   // round-to-nearest-even
    return (unsigned short)(u >> 16);
}
__device__ __forceinline__ unsigned int pk2(float lo, float hi) {
    return (unsigned int)f2bf(lo) | ((unsigned int)f2bf(hi) << 16);
}

// Subtile layout within one [256 r][32 k] tile (ushort offset):
//   (r>>4)*512 + (k>>3)*128 + (r&15)*8 + (k&7)
// Frag read (lane l): byte = rt*1024 + l4*256 + l15*16 -> contiguous 1 KiB
// per frag across the wave: conflict-free ds_read_b128 (R2/R6-verified).

// ---------------- w converter (+ group starts) ----------------

__global__ __launch_bounds__(256)
void convert_w(const float* __restrict__ w, const int* __restrict__ idx,
               unsigned short* __restrict__ wsw, int* __restrict__ starts)
{
    const int t = blockIdx.x * 256 + threadIdx.x;    // 524288 tasks
    const int g   = t >> 16;
    const int rem = t & 65535;
    const int u0  = (rem >> 9) << 2;                 // 4 k-rows
    const int v   = rem & 511;
    const float* src = w + ((size_t)g << 18) + (size_t)u0 * Vd + v;
    us4 p;
    p[0] = f2bf(src[0]);
    p[1] = f2bf(src[Vd]);
    p[2] = f2bf(src[2 * Vd]);
    p[3] = f2bf(src[3 * Vd]);
    const int r = v & 255, k = u0 & 31;
    const int tile = (g * NBN + (v >> 8)) * KT + (u0 >> 5);
    const int off  = tile * TILE_US
                   + ((r >> 4) << 9) + ((k >> 3) << 7) + ((r & 15) << 3) + (k & 7);
    *(us4*)(wsw + off) = p;

    if (blockIdx.x == 0 && threadIdx.x < 9) {
        const int gq = threadIdx.x;
        int lo = 0;
        if (gq >= 8) lo = Zd;
        else {
            int hi = Zd;
            while (lo < hi) { int mid = (lo + hi) >> 1;
                              if (idx[mid] < gq) lo = mid + 1; else hi = mid; }
        }
        starts[gq] = lo;
    }
}

// ---------------- GEMM ----------------

#define LDA(KTV, A0, A1, A2, A3) do {                                         \
    const float* p_ = ax + (KTV) * BK;                                        \
    A0 = *(const float4v*)(p_);                                               \
    A1 = *(const float4v*)(p_ + 4);                                           \
    A2 = *(const float4v*)(p_ + 8);                                           \
    A3 = *(const float4v*)(p_ + 12); } while (0)

#define CVW(BUF, A0, A1, A2, A3) do {                                         \
    u32x4 w1_, w2_;                                                           \
    w1_[0] = pk2(A0[0], A0[1]); w1_[1] = pk2(A0[2], A0[3]);                   \
    w1_[2] = pk2(A1[0], A1[1]); w1_[3] = pk2(A1[2], A1[3]);                   \
    w2_[0] = pk2(A2[0], A2[1]); w2_[1] = pk2(A2[2], A2[3]);                   \
    w2_[2] = pk2(A3[0], A3[1]); w2_[3] = pk2(A3[2], A3[3]);                   \
    *(u32x4*)(&BUF[aw])       = w1_;                                          \
    *(u32x4*)(&BUF[aw + 128]) = w2_; } while (0)

#define GLB(KTV, BUF) do {                                                    \
    const unsigned short* s_ = wB + (size_t)(KTV) * TILE_US;                  \
    __builtin_amdgcn_global_load_lds((gbl_uint*)(s_ + bo),                    \
                                     (lds_uint*)(&BUF[bo]), 16, 0, 0);        \
    __builtin_amdgcn_global_load_lds((gbl_uint*)(s_ + bo + 4096),             \
                                     (lds_uint*)(&BUF[bo + 4096]), 16, 0, 0); \
  } while (0)

#define CMP(ABUF, BBUF) do {                                                  \
    bf16x8 a_[8], b_[4];                                                      \
    _Pragma("unroll")                                                         \
    for (int mi_ = 0; mi_ < 8; ++mi_)                                         \
        a_[mi_] = *(const bf16x8*)(&ABUF[((wm8 + mi_) << 9) + fr]);           \
    _Pragma("unroll")                                                         \
    for (int ni_ = 0; ni_ < 4; ++ni_)                                         \
        b_[ni_] = *(const bf16x8*)(&BBUF[((wn4 + ni_) << 9) + fr]);           \
    _Pragma("unroll")                                                         \
    for (int mi_ = 0; mi_ < 8; ++mi_)                                         \
        _Pragma("unroll")                                                     \
        for (int ni_ = 0; ni_ < 4; ++ni_)                                     \
            acc[mi_][ni_] = __builtin_amdgcn_mfma_f32_16x16x32_bf16(          \
                a_[mi_], b_[ni_], acc[mi_][ni_], 0, 0, 0);                    \
  } while (0)

#define WAITBAR(N) do {                                                       \
    asm volatile("s_waitcnt vmcnt(" #N ") lgkmcnt(0)" ::: "memory");          \
    __builtin_amdgcn_s_barrier(); } while (0)

__global__ __launch_bounds__(512, 2)
void sgl_gemm(const float* __restrict__ x,
              const unsigned short* __restrict__ wsw,
              const int* __restrict__ starts,
              const float* __restrict__ coeff,
              float* __restrict__ y)
{
    __shared__ unsigned short As[2][TILE_US];
    __shared__ unsigned short Bs[2][TILE_US];    // 64 KiB total

    const int tid = threadIdx.x, lane = tid & 63, wave = tid >> 6;
    const int l15 = lane & 15, l4 = lane >> 4;

    // bijective XCD swizzle (m204): nwg=270, q=33, r=6; consecutive wk pairs
    // share bmp -> both bn-blocks of one x-panel land on one XCD (L2 reuse).
    const int bid = blockIdx.x;
    const int xcd = bid & 7, io = bid >> 3;
    const int wk  = (xcd < 6) ? xcd * 34 + io : 204 + (xcd - 6) * 33 + io;
    const int bmp = wk >> 1, bn = wk & 1;

    // locate group for this padded row-block
    int s[9];
#pragma unroll
    for (int i = 0; i < 9; ++i) s[i] = starts[i];
    int g = -1, lblk = 0, ab = 0;
#pragma unroll
    for (int gg = 0; gg < 8; ++gg) {
        const int c  = s[gg + 1] - s[gg];
        const int nb = (c + BM - 1) >> 8;
        if (g < 0 && bmp < ab + nb) { g = gg; lblk = bmp - ab; }
        ab += nb;
    }
    if (g < 0) return;
    const int start = s[g];
    const int cnt   = s[g + 1] - s[g];
    const int j0    = lblk << 8;

    // A: thread t -> row t>>1 (coalesced pairs), k-half (t&1)*16; clamp pads
    const int ar = tid >> 1;                 // 0..255
    const int ak = (tid & 1) << 4;
    const int rc = (j0 + ar < cnt) ? (j0 + ar) : (cnt - 1);
    const float* ax = x + (size_t)(start + rc) * Ud + ak;
    const int aw = ((ar >> 4) << 9) + ((ak >> 3) << 7) + ((ar & 15) << 3);

    // B: linear gload_lds from pre-tiled ws (16 KiB tile, 2 x 16B per thread)
    const unsigned short* wB = wsw + (size_t)((g * NBN + bn) * KT) * TILE_US;
    const int bo = tid * 8;

    const int wm8 = (wave >> 2) << 3;        // 0 or 8 (2 m-groups of 128 rows)
    const int wn4 = (wave & 3) << 2;         // 0,4,8,12 (4 n-groups of 64)
    const int fr  = (l4 << 7) + (l15 << 3);

    f32x4 acc[8][4];
#pragma unroll
    for (int mi = 0; mi < 8; ++mi)
#pragma unroll
        for (int ni = 0; ni < 4; ++ni)
            acc[mi][ni] = f32x4{0.f, 0.f, 0.f, 0.f};

    float4v e0, e1, e2, e3, o0, o1, o2, o3;

    // prologue: A(0)->e, B(0), A(1)->o ; cvt A(0); barrier leaves A(1) flying
    LDA(0, e0, e1, e2, e3);
    __builtin_amdgcn_sched_barrier(0);
    GLB(0, Bs[0]);
    __builtin_amdgcn_sched_barrier(0);
    LDA(1, o0, o1, o2, o3);
    __builtin_amdgcn_sched_barrier(0);
    CVW(As[0], e0, e1, e2, e3);
    WAITBAR(4);

    // steady state: iter kt stages B(kt+1)+A(kt+2), cvts A(kt+1), computes kt.
    // Barrier waits vmcnt(4): B(kt+1) done, A(kt+2) reg-loads stay in flight.
#pragma unroll
    for (int kt = 0; kt < 14; ++kt) {
        if ((kt & 1) == 0) {
            GLB(kt + 1, Bs[1]);
            __builtin_amdgcn_sched_barrier(0);
            LDA(kt + 2, e0, e1, e2, e3);
            __builtin_amdgcn_sched_barrier(0);
            CVW(As[1], o0, o1, o2, o3);
            CMP(As[0], Bs[0]);
        } else {
            GLB(kt + 1, Bs[0]);
            __builtin_amdgcn_sched_barrier(0);
            LDA(kt + 2, o0, o1, o2, o3);
            __builtin_amdgcn_sched_barrier(0);
            CVW(As[0], e0, e1, e2, e3);
            CMP(As[1], Bs[1]);
        }
        WAITBAR(4);
    }
    // kt = 14 (A(15) is in o; no more prefetch)
    GLB(15, Bs[1]);
    __builtin_amdgcn_sched_barrier(0);
    CVW(As[1], o0, o1, o2, o3);
    CMP(As[0], Bs[0]);
    WAITBAR(0);
    // kt = 15
    CMP(As[1], Bs[1]);

    // epilogue: C/D col=lane&15, row=(lane>>4)*4+q; mask padded rows
    const float cf = coeff[0];
    const bool full = (j0 + BM) <= cnt;
#pragma unroll
    for (int mi = 0; mi < 8; ++mi) {
        const int rb = ((wave >> 2) << 7) + mi * 16 + l4 * 4;
#pragma unroll
        for (int ni = 0; ni < 4; ++ni) {
            const int c = bn * BN + ((wave & 3) << 6) + ni * 16 + l15;
#pragma unroll
            for (int q = 0; q < 4; ++q) {
                if (full || (j0 + rb + q) < cnt)
                    y[(size_t)(start + j0 + rb + q) * Vd + c] = acc[mi][ni][q] * cf;
            }
        }
    }
}

// ---------------- safety-net fallback (ws too small; not expected) --------

__global__ __launch_bounds__(256)
void sgl_naive(const float* __restrict__ w, const float* __restrict__ x,
               const int* __restrict__ idx, const float* __restrict__ coeff,
               float* __restrict__ y)
{
    __shared__ float xs[Ud];
    const int z = blockIdx.x;
    const int g = idx[z];
    for (int u = threadIdx.x; u < Ud; u += 256) xs[u] = x[(size_t)z * Ud + u];
    __syncthreads();
    const float* Wg = w + (size_t)g * (Ud * Vd);
    const float cf = coeff[0];
    for (int v = threadIdx.x; v < Vd; v += 256) {
        float acc = 0.f;
        for (int u = 0; u < Ud; ++u) acc += xs[u] * Wg[(size_t)u * Vd + v];
        y[(size_t)z * Vd + v] = acc * cf;
    }
}

extern "C" void kernel_launch(void* const* d_in, const int* in_sizes, int n_in,
                              void* d_out, int out_size, void* d_ws, size_t ws_size,
                              hipStream_t stream) {
    const float* w     = (const float*)d_in[0];
    const float* x     = (const float*)d_in[1];
    const int*   idx   = (const int*)d_in[2];
    const float* coeff = (const float*)d_in[3];
    float* y = (float*)d_out;

    if (ws_size >= WS_NEEDED) {
        unsigned short* wsw = (unsigned short*)d_ws;
        int* starts = (int*)((char*)d_ws + (size_t)WSW_US * 2);
        hipLaunchKernelGGL(convert_w, dim3(2048), dim3(256), 0, stream,
                           w, idx, wsw, starts);
        hipLaunchKernelGGL(sgl_gemm, dim3(GRID_GEMM), dim3(512), 0, stream,
                           x, wsw, starts, coeff, y);
    } else {
        hipLaunchKernelGGL(sgl_naive, dim3(Zd), dim3(256), 0, stream,
                           w, x, idx, coeff, y);
    }
}

// Round 9
// 51.042 us; speedup vs baseline: 1.8716x; 1.2235x over previous
//
#include <hip/hip_runtime.h>
#include <stdint.h>

// Grouped linear: y[z] = coeff * x[z] @ W[idx[z]], idx sorted.
// C=8, U=V=512, Z=32768, fp32 in/out, bf16 MFMA compute.
//
// R9 = R6's A-path (coalesced fp32 reg-stage -> cvt -> ds_write, depth-2) +
// R7's B-path (3 rotating LDS buffers, global_load_lds issued 2 K-steps
// ahead) + 1052-block grid (load-balanced, 3-4 blocks/CU). Steady state:
// outstanding VM at each barrier = {B(kt+1), A(kt+1)} = 6 -> vmcnt(6) is a
// no-op; barrier only drains lgkm. Zero VM drains in the main loop.

#define Cg 8
#define Ud 512
#define Vd 512
#define Zd 32768

#define BM 128
#define BN 128
#define BK 32
#define KT 16

#define TILE_US 4096             // 128 x 32 bf16 = 8 KiB
#define NBN 4
#define NBM_MAX 263              // sum ceil(cnt_g/128) <= 256+7
#define GRID_GEMM (NBM_MAX * NBN)    // 1052

#define WSW_US (Cg * NBN * KT * TILE_US)     // 4 MiB of bf16
#define WS_NEEDED ((size_t)WSW_US * 2 + 64)

typedef __attribute__((ext_vector_type(8))) short bf16x8;
typedef __attribute__((ext_vector_type(4))) float f32x4;
typedef __attribute__((ext_vector_type(4))) unsigned short us4;
typedef __attribute__((ext_vector_type(4))) float float4v;
typedef __attribute__((ext_vector_type(4))) unsigned int u32x4;

typedef __attribute__((address_space(3))) unsigned int lds_uint;
typedef const __attribute__((address_space(1))) unsigned int gbl_uint;

__device__ __forceinline__ unsigned short f2bf(float f) {
    unsigned int u = __float_as_uint(f);
    u += 0x7fffu + ((u >> 16) & 1u);   // round-to-nearest-even
    return (unsigned short)(u >> 16);
}
__device__ __forceinline__ unsigned int pk2(float lo, float hi) {
    return (unsigned int)f2bf(lo) | ((unsigned int)f2bf(hi) << 16);
}

// Subtile layout within one [128 r][32 k] tile (ushort offset):
//   (r>>4)*512 + (k>>3)*128 + (r&15)*8 + (k&7)
// Frag read (lane l): byte = rt*1024 + l4*256 + l15*16 -> contiguous 1 KiB
// per frag across the wave: conflict-free ds_read_b128 (R2/R6-verified).

// ---------------- w converter (+ group starts) ----------------

__global__ __launch_bounds__(256)
void convert_w(const float* __restrict__ w, const int* __restrict__ idx,
               unsigned short* __restrict__ wsw, int* __restrict__ starts)
{
    const int t = blockIdx.x * 256 + threadIdx.x;    // 524288 tasks
    const int g   = t >> 16;
    const int rem = t & 65535;
    const int u0  = (rem >> 9) << 2;                 // 4 k-rows
    const int v   = rem & 511;
    const float* src = w + ((size_t)g << 18) + (size_t)u0 * Vd + v;
    us4 p;
    p[0] = f2bf(src[0]);
    p[1] = f2bf(src[Vd]);
    p[2] = f2bf(src[2 * Vd]);
    p[3] = f2bf(src[3 * Vd]);
    const int r = v & 127, k = u0 & 31;
    const int tile = (g * NBN + (v >> 7)) * KT + (u0 >> 5);
    const int off  = tile * TILE_US
                   + ((r >> 4) << 9) + ((k >> 3) << 7) + ((r & 15) << 3) + (k & 7);
    *(us4*)(wsw + off) = p;

    if (blockIdx.x == 0 && threadIdx.x < 9) {
        const int gq = threadIdx.x;
        int lo = 0;
        if (gq >= 8) lo = Zd;
        else {
            int hi = Zd;
            while (lo < hi) { int mid = (lo + hi) >> 1;
                              if (idx[mid] < gq) lo = mid + 1; else hi = mid; }
        }
        starts[gq] = lo;
    }
}

// ---------------- GEMM ----------------

#define LDA(KTV, A0, A1, A2, A3) do {                                         \
    const float* p_ = ax + (KTV) * BK;                                        \
    A0 = *(const float4v*)(p_);                                               \
    A1 = *(const float4v*)(p_ + 4);                                           \
    A2 = *(const float4v*)(p_ + 8);                                           \
    A3 = *(const float4v*)(p_ + 12); } while (0)

#define CVW(BUF, A0, A1, A2, A3) do {                                         \
    u32x4 w1_, w2_;                                                           \
    w1_[0] = pk2(A0[0], A0[1]); w1_[1] = pk2(A0[2], A0[3]);                   \
    w1_[2] = pk2(A1[0], A1[1]); w1_[3] = pk2(A1[2], A1[3]);                   \
    w2_[0] = pk2(A2[0], A2[1]); w2_[1] = pk2(A2[2], A2[3]);                   \
    w2_[2] = pk2(A3[0], A3[1]); w2_[3] = pk2(A3[2], A3[3]);                   \
    *(u32x4*)(&BUF[aw])       = w1_;                                          \
    *(u32x4*)(&BUF[aw + 128]) = w2_; } while (0)

#define GLB(KTV, J) do {                                                      \
    const unsigned short* s_ = wB + (size_t)(KTV) * TILE_US;                  \
    __builtin_amdgcn_global_load_lds((gbl_uint*)(s_ + bo),                    \
                                     (lds_uint*)(&Bs[J][bo]), 16, 0, 0);      \
    __builtin_amdgcn_global_load_lds((gbl_uint*)(s_ + bo + 2048),             \
                                     (lds_uint*)(&Bs[J][bo + 2048]), 16, 0, 0); \
  } while (0)

#define CMP(ABUF, J) do {                                                     \
    bf16x8 a_[4], b_[4];                                                      \
    _Pragma("unroll")                                                         \
    for (int mi_ = 0; mi_ < 4; ++mi_)                                         \
        a_[mi_] = *(const bf16x8*)(&ABUF[((wm4 + mi_) << 9) + fr]);           \
    _Pragma("unroll")                                                         \
    for (int ni_ = 0; ni_ < 4; ++ni_)                                         \
        b_[ni_] = *(const bf16x8*)(&Bs[J][((wn4 + ni_) << 9) + fr]);          \
    _Pragma("unroll")                                                         \
    for (int mi_ = 0; mi_ < 4; ++mi_)                                         \
        _Pragma("unroll")                                                     \
        for (int ni_ = 0; ni_ < 4; ++ni_)                                     \
            acc[mi_][ni_] = __builtin_amdgcn_mfma_f32_16x16x32_bf16(          \
                a_[mi_], b_[ni_], acc[mi_][ni_], 0, 0, 0);                    \
  } while (0)

#define WAITBAR(N) do {                                                       \
    asm volatile("s_waitcnt vmcnt(" #N ") lgkmcnt(0)" ::: "memory");          \
    __builtin_amdgcn_s_barrier(); } while (0)

#define SBAR() __builtin_amdgcn_sched_barrier(0)

__global__ __launch_bounds__(256, 3)
void sgl_gemm(const float* __restrict__ x,
              const unsigned short* __restrict__ wsw,
              const int* __restrict__ starts,
              const float* __restrict__ coeff,
              float* __restrict__ y)
{
    __shared__ unsigned short As[2][TILE_US];    // 16 KiB
    __shared__ unsigned short Bs[3][TILE_US];    // 24 KiB

    const int tid = threadIdx.x, lane = tid & 63, wave = tid >> 6;
    const int l15 = lane & 15, l4 = lane >> 4;

    // bijective XCD swizzle (m204): nwg=1052, q=131, r=4; consecutive wk
    // share bmp -> the 4 bn-blocks of one x-panel land on one XCD (L2 reuse).
    const int bid = blockIdx.x;
    const int xcd = bid & 7, io = bid >> 3;
    const int wk  = (xcd < 4) ? xcd * 132 + io : 528 + (xcd - 4) * 131 + io;
    const int bmp = wk >> 2, bn = wk & 3;

    // locate group for this padded row-block
    int s[9];
#pragma unroll
    for (int i = 0; i < 9; ++i) s[i] = starts[i];
    int g = -1, lblk = 0, ab = 0;
#pragma unroll
    for (int gg = 0; gg < 8; ++gg) {
        const int c  = s[gg + 1] - s[gg];
        const int nb = (c + BM - 1) >> 7;
        if (g < 0 && bmp < ab + nb) { g = gg; lblk = bmp - ab; }
        ab += nb;
    }
    if (g < 0) return;
    const int start = s[g];
    const int cnt   = s[g + 1] - s[g];
    const int j0    = lblk << 7;

    // A: thread t -> row t>>1 (coalesced pairs), k-half (t&1)*16; clamp pads
    const int ar = tid >> 1;
    const int ak = (tid & 1) << 4;
    const int rc = (j0 + ar < cnt) ? (j0 + ar) : (cnt - 1);
    const float* ax = x + (size_t)(start + rc) * Ud + ak;
    const int aw = ((ar >> 4) << 9) + ((ak >> 3) << 7) + ((ar & 15) << 3);

    // B: linear gload_lds from pre-tiled ws (8 KiB tile, 2 x 16B per thread)
    const unsigned short* wB = wsw + (size_t)((g * NBN + bn) * KT) * TILE_US;
    const int bo = tid * 8;

    const int wm4 = (wave >> 1) << 2;
    const int wn4 = (wave & 1) << 2;
    const int fr  = (l4 << 7) + (l15 << 3);

    f32x4 acc[4][4];
#pragma unroll
    for (int mi = 0; mi < 4; ++mi)
#pragma unroll
        for (int ni = 0; ni < 4; ++ni)
            acc[mi][ni] = f32x4{0.f, 0.f, 0.f, 0.f};

    float4v e0, e1, e2, e3, o0, o1, o2, o3;

    // prologue: B0,B1 + A0,A1 in flight; cvt A0; barrier leaves {B1,A1}=6.
    GLB(0, 0);
    SBAR();
    LDA(0, e0, e1, e2, e3);
    SBAR();
    GLB(1, 1);
    SBAR();
    LDA(1, o0, o1, o2, o3);
    SBAR();
    CVW(As[0], e0, e1, e2, e3);    // compiler waits A0 (drains B0 too)
    WAITBAR(6);                    // vmcnt no-op; lgkm drain; B0 ready

    // steady state kt=0..13: issue B(kt+2), A(kt+2); cvt A(kt+1); compute kt.
    // At barrier: outstanding = {B(kt+2), A(kt+2)} = 6 -> vmcnt(6) no-op.
#pragma unroll
    for (int kt = 0; kt < 14; ++kt) {
        GLB(kt + 2, (kt + 2) % 3);
        SBAR();
        if ((kt & 1) == 0) {
            LDA(kt + 2, e0, e1, e2, e3);
            SBAR();
            CVW(As[1], o0, o1, o2, o3);
            CMP(As[0], kt % 3);
        } else {
            LDA(kt + 2, o0, o1, o2, o3);
            SBAR();
            CVW(As[0], e0, e1, e2, e3);
            CMP(As[1], kt % 3);
        }
        WAITBAR(6);
    }
    // kt = 14: nothing left to issue; A15 is in o (loop parity: kt=14 even)
    CVW(As[1], o0, o1, o2, o3);
    CMP(As[0], 14 % 3);
    WAITBAR(0);
    // kt = 15
    CMP(As[1], 15 % 3);

    // epilogue: C/D col=lane&15, row=(lane>>4)*4+q; mask padded rows
    const float cf = coeff[0];
    const bool full = (j0 + BM) <= cnt;
#pragma unroll
    for (int mi = 0; mi < 4; ++mi) {
        const int rb = ((wave >> 1) << 6) + mi * 16 + l4 * 4;
#pragma unroll
        for (int ni = 0; ni < 4; ++ni) {
            const int c = bn * BN + ((wave & 1) << 6) + ni * 16 + l15;
#pragma unroll
            for (int q = 0; q < 4; ++q) {
                if (full || (j0 + rb + q) < cnt)
                    y[(size_t)(start + j0 + rb + q) * Vd + c] = acc[mi][ni][q] * cf;
            }
        }
    }
}

// ---------------- safety-net fallback (ws too small; not expected) --------

__global__ __launch_bounds__(256)
void sgl_naive(const float* __restrict__ w, const float* __restrict__ x,
               const int* __restrict__ idx, const float* __restrict__ coeff,
               float* __restrict__ y)
{
    __shared__ float xs[Ud];
    const int z = blockIdx.x;
    const int g = idx[z];
    for (int u = threadIdx.x; u < Ud; u += 256) xs[u] = x[(size_t)z * Ud + u];
    __syncthreads();
    const float* Wg = w + (size_t)g * (Ud * Vd);
    const float cf = coeff[0];
    for (int v = threadIdx.x; v < Vd; v += 256) {
        float acc = 0.f;
        for (int u = 0; u < Ud; ++u) acc += xs[u] * Wg[(size_t)u * Vd + v];
        y[(size_t)z * Vd + v] = acc * cf;
    }
}

extern "C" void kernel_launch(void* const* d_in, const int* in_sizes, int n_in,
                              void* d_out, int out_size, void* d_ws, size_t ws_size,
                              hipStream_t stream) {
    const float* w     = (const float*)d_in[0];
    const float* x     = (const float*)d_in[1];
    const int*   idx   = (const int*)d_in[2];
    const float* coeff = (const float*)d_in[3];
    float* y = (float*)d_out;

    if (ws_size >= WS_NEEDED) {
        unsigned short* wsw = (unsigned short*)d_ws;
        int* starts = (int*)((char*)d_ws + (size_t)WSW_US * 2);
        hipLaunchKernelGGL(convert_w, dim3(2048), dim3(256), 0, stream,
                           w, idx, wsw, starts);
        hipLaunchKernelGGL(sgl_gemm, dim3(GRID_GEMM), dim3(256), 0, stream,
                           x, wsw, starts, coeff, y);
    } else {
        hipLaunchKernelGGL(sgl_naive, dim3(Zd), dim3(256), 0, stream,
                           w, x, idx, coeff, y);
    }
}